// Round 1
// baseline (21.486 us; speedup 1.0000x reference)
//
#include <hip/hip_runtime.h>

#define KS   7
#define KK   49
#define MIDJ 24
#define H    256
#define W    320
#define HW   (H * W)
#define BS   4
#define ITERS 6

// Fully fused DYSPN step:
//   out[b,p] = (sum_j k[b,j,p]*a[b,i,ring(j),p]*patch_j) / (sum_j |k*a|)
// ring(j) = Chebyshev distance of tap j from center (verified against the
// line7/line5/line3 index lists in the reference).
__global__ __launch_bounds__(256) void dyspn_kernel(
    const float* __restrict__ kern,    // (BS, KK, HW)
    const float* __restrict__ input,   // (BS, 1, H, W)
    const float* __restrict__ input0,  // (BS, 1, H, W)
    const float* __restrict__ att,     // (BS, ITERS, 4, HW)
    const int*   __restrict__ i_ptr,   // scalar
    float*       __restrict__ out)     // (BS, 1, H, W)
{
    const int i_sel = *i_ptr;  // uniform scalar load

    int t   = blockIdx.x * blockDim.x + threadIdx.x;  // 2 pixels per thread
    int idx = t * 2;
    if (idx >= BS * HW) return;

    int b = idx / HW;
    int p = idx - b * HW;          // even
    int y = p / W;
    int x = p - y * W;

    // attention[b, i_sel, r, p..p+1]
    const float* attb = att + ((size_t)(b * ITERS + i_sel)) * 4 * HW + p;
    float2 a0 = *(const float2*)(attb);
    float2 a1 = *(const float2*)(attb + HW);
    float2 a2 = *(const float2*)(attb + 2 * HW);
    float2 a3 = *(const float2*)(attb + 3 * HW);
    const float ar0[4] = {a0.x, a1.x, a2.x, a3.x};
    const float ar1[4] = {a0.y, a1.y, a2.y, a3.y};

    const float* kb  = kern + (size_t)b * KK * HW + p;
    const float* inb = input + (size_t)b * HW;

    float acc0 = 0.f, acc1 = 0.f, den0 = 0.f, den1 = 0.f;

#pragma unroll
    for (int j = 0; j < KK; ++j) {
        const int dy = j / KS - 3;                       // compile-time
        const int dx = j % KS - 3;                       // compile-time
        const int r  = max(dy < 0 ? -dy : dy,
                           dx < 0 ? -dx : dx);           // ring id, compile-time

        float2 kv = *(const float2*)(kb + (size_t)j * HW);
        float v0 = kv.x * ar0[r];
        float v1 = kv.y * ar1[r];
        den0 += fabsf(v0);
        den1 += fabsf(v1);

        float p0, p1;
        if (j == MIDJ) {
            float2 z = *(const float2*)(input0 + (size_t)b * HW + p);
            p0 = z.x; p1 = z.y;
        } else {
            const int yy = y + dy;
            if (yy >= 0 && yy < H) {
                const int x0 = x + dx;
                const int x1 = x0 + 1;
                const float* row = inb + yy * W;
                p0 = (x0 >= 0 && x0 < W) ? row[x0] : 0.f;
                p1 = (x1 >= 0 && x1 < W) ? row[x1] : 0.f;
            } else {
                p0 = 0.f; p1 = 0.f;
            }
        }
        acc0 += v0 * p0;
        acc1 += v1 * p1;
    }

    float2 o;
    o.x = acc0 / den0;
    o.y = acc1 / den1;
    *(float2*)(out + (size_t)b * HW + p) = o;
}

extern "C" void kernel_launch(void* const* d_in, const int* in_sizes, int n_in,
                              void* d_out, int out_size, void* d_ws, size_t ws_size,
                              hipStream_t stream) {
    const float* kern   = (const float*)d_in[0];
    const float* input  = (const float*)d_in[1];
    const float* input0 = (const float*)d_in[2];
    const float* att    = (const float*)d_in[3];
    const int*   i_ptr  = (const int*)d_in[4];
    float* out = (float*)d_out;

    const int total_threads = BS * HW / 2;   // 163840
    const int block = 256;
    const int grid  = (total_threads + block - 1) / block;  // 640

    dyspn_kernel<<<grid, block, 0, stream>>>(kern, input, input0, att, i_ptr, out);
}